// Round 3
// baseline (118.543 us; speedup 1.0000x reference)
//
#include <hip/hip_runtime.h>
#include <math.h>

// MDN_module: B rows, each: h = relu(x@W1 + b1) [64], out = h@W2 + b2 [4]
// mu = out[0:2], lv = out[2:4]; Lyapunov rescale; rsample fx; grand-sum logp_y.
//
// R6 strategy (weight-overhead amortization + streaming hints, on top of R5):
//   R4 (NPAIR=4/occ4) vs R5 (NPAIR=1/occ8) differed by <1us -> neither
//   pressure nor occupancy is the limiter. Remaining candidate: at NPAIR=1
//   each chunk's 7 wave-uniform s_loads + lgkmcnt waits + splats serve only
//   one row-pair of FMAs (~50% scalar-side overhead). Fix:
//   1. NPAIR=2, GRID=2048, launch_bounds(256,8): halves weight-handling share
//      per row, doubles FMA dep-chain ILP; ~54 persistent VGPRs still fits
//      the 64-VGPR cap for 8 waves/SIMD.
//   2. x/y/eps loads and fx store are touch-once 67 MB streams ->
//      __builtin_nontemporal_load/store (no L2 write-allocate/pollution).
//   3. y/eps issued between chunk 11 and 12 (latency covered, short live range).
//
//   W1 [2][64] row-major; W2 [64][4] row-major (float4/row); Wv [2][2]
//   d_out: fx (2B floats) then logp_y (1 float at index 2B)

typedef float v2f __attribute__((ext_vector_type(2)));
typedef float v4f __attribute__((ext_vector_type(4)));

#define GRID 2048
#define BLOCK 256
#define NPAIR 2            // row-pairs (float4) per thread; 2048*256*2 = exact fit
#define LOG_2PI 1.8378770664093453f

__device__ __forceinline__ float rcp_fast(float v) { return __builtin_amdgcn_rcpf(v); }
__device__ __forceinline__ v2f splat(float s) { v2f r; r.x = s; r.y = s; return r; }

// One 4-hidden-unit chunk of the MLP applied to NPAIR row-pairs.
// Weight addresses are wave-uniform -> s_load; no LDS, no per-lane VMEM.
__device__ __forceinline__ void mlp_chunk(int c,
                                          const float* __restrict__ W1,
                                          const float* __restrict__ b1,
                                          const float* __restrict__ W2,
                                          const v2f (&X0)[NPAIR], const v2f (&X1)[NPAIR],
                                          v2f (&A0)[NPAIR], v2f (&A1)[NPAIR],
                                          v2f (&A2)[NPAIR], v2f (&A3)[NPAIR])
{
    const float4 wa = *reinterpret_cast<const float4*>(W1 + 4 * c);        // W1[0][4c..]
    const float4 wb = *reinterpret_cast<const float4*>(W1 + 64 + 4 * c);   // W1[1][4c..]
    const float4 bb = *reinterpret_cast<const float4*>(b1 + 4 * c);
    const float4 w2r[4] = {
        reinterpret_cast<const float4*>(W2)[4 * c + 0],
        reinterpret_cast<const float4*>(W2)[4 * c + 1],
        reinterpret_cast<const float4*>(W2)[4 * c + 2],
        reinterpret_cast<const float4*>(W2)[4 * c + 3],
    };
    #pragma unroll
    for (int j = 0; j < 4; ++j) {
        const v2f waj = splat((&wa.x)[j]);
        const v2f wbj = splat((&wb.x)[j]);
        const v2f bj  = splat((&bb.x)[j]);
        const v2f w20 = splat(w2r[j].x);
        const v2f w21 = splat(w2r[j].y);
        const v2f w22 = splat(w2r[j].z);
        const v2f w23 = splat(w2r[j].w);
        #pragma unroll
        for (int p = 0; p < NPAIR; ++p) {
            v2f h = __builtin_elementwise_fma(X1[p], wbj, bj);
            h = __builtin_elementwise_fma(X0[p], waj, h);
            h = __builtin_elementwise_max(h, splat(0.f));
            A0[p] = __builtin_elementwise_fma(h, w20, A0[p]);
            A1[p] = __builtin_elementwise_fma(h, w21, A1[p]);
            A2[p] = __builtin_elementwise_fma(h, w22, A2[p]);
            A3[p] = __builtin_elementwise_fma(h, w23, A3[p]);
        }
    }
}

__launch_bounds__(BLOCK, 8)
__global__ void mdn_kernel(const float* __restrict__ x,
                           const float* __restrict__ y,
                           const float* __restrict__ eps,
                           const float* __restrict__ W1,
                           const float* __restrict__ b1,
                           const float* __restrict__ W2,
                           const float* __restrict__ b2,
                           const float* __restrict__ Wv,
                           float* __restrict__ fx_out,
                           float* __restrict__ block_part,
                           int n_pairs)
{
    __shared__ float s_part[BLOCK / 64];

    const int t = threadIdx.x;
    const int T = GRID * BLOCK;
    const int g = blockIdx.x * BLOCK + t;

    // uniform scalars -> s_load
    const float b2_0 = b2[0], b2_1 = b2[1], b2_2 = b2[2], b2_3 = b2[3];
    const float wv00 = Wv[0], wv01 = Wv[1], wv10 = Wv[2], wv11 = Wv[3];

    v2f X0[NPAIR], X1[NPAIR], Vx[NPAIR];
    v2f A0[NPAIR], A1[NPAIR], A2[NPAIR], A3[NPAIR];

    // ---- prologue: x loads only (nontemporal: touch-once stream) ----
    #pragma unroll
    for (int p = 0; p < NPAIR; ++p) {
        const int rp = g + p * T;
        v4f xv = {0.f, 0.f, 0.f, 0.f};
        if (rp < n_pairs)
            xv = __builtin_nontemporal_load(reinterpret_cast<const v4f*>(x) + rp);
        X0[p].x = xv[0]; X0[p].y = xv[2];   // rows 2rp, 2rp+1: x[0]
        X1[p].x = xv[1]; X1[p].y = xv[3];   // rows 2rp, 2rp+1: x[1]
        A0[p] = splat(b2_0); A1[p] = splat(b2_1);
        A2[p] = splat(b2_2); A3[p] = splat(b2_3);
    }
    // V(x) now: x dies with the MLP loop (small epilogue live set).
    #pragma unroll
    for (int p = 0; p < NPAIR; ++p) {
        const v2f zx0 = __builtin_elementwise_fma(X0[p], splat(wv00), X1[p] * splat(wv10));
        const v2f zx1 = __builtin_elementwise_fma(X0[p], splat(wv01), X1[p] * splat(wv11));
        Vx[p] = __builtin_elementwise_fma(zx0, zx0,
                __builtin_elementwise_fma(zx1, zx1, splat(1e-3f)));
    }

    // ---- MLP chunks 0..11 ----
    #pragma unroll 2
    for (int c = 0; c < 12; ++c)
        mlp_chunk(c, W1, b1, W2, X0, X1, A0, A1, A2, A3);

    // ---- issue y/eps loads: tail chunks + inter-wave overlap cover latency ----
    v4f yv[NPAIR], ev[NPAIR];
    #pragma unroll
    for (int p = 0; p < NPAIR; ++p) {
        const int rp = g + p * T;
        yv[p] = (v4f){0.f, 0.f, 0.f, 0.f};
        ev[p] = (v4f){0.f, 0.f, 0.f, 0.f};
        if (rp < n_pairs) {
            yv[p] = __builtin_nontemporal_load(reinterpret_cast<const v4f*>(y) + rp);
            ev[p] = __builtin_nontemporal_load(reinterpret_cast<const v4f*>(eps) + rp);
        }
    }

    // ---- MLP chunks 12..15 ----
    #pragma unroll 2
    for (int c = 12; c < 16; ++c)
        mlp_chunk(c, W1, b1, W2, X0, X1, A0, A1, A2, A3);

    // ---- epilogue, v2f row-pair form (all operands in registers) ----
    v2f lsum = splat(0.f);
    #pragma unroll
    for (int p = 0; p < NPAIR; ++p) {
        const int rp = g + p * T;
        const v2f mu0 = A0[p], mu1 = A1[p], lv0 = A2[p], lv1 = A3[p];
        // V(mu)
        const v2f zm0 = __builtin_elementwise_fma(mu0, splat(wv00), mu1 * splat(wv10));
        const v2f zm1 = __builtin_elementwise_fma(mu0, splat(wv01), mu1 * splat(wv11));
        const v2f Vmu = __builtin_elementwise_fma(zm0, zm0,
                        __builtin_elementwise_fma(zm1, zm1, splat(1e-3f)));
        // scale = min(beta*Vx, Vmu)/Vmu
        const v2f num = __builtin_elementwise_min(splat(0.99f) * Vx[p], Vmu);
        v2f scale;
        scale.x = num.x * rcp_fast(Vmu.x);
        scale.y = num.y * rcp_fast(Vmu.y);
        const v2f ms0 = mu0 * scale, ms1 = mu1 * scale;
        // rsample: fx = ms + exp(lv/2)*eps ; inv-var = exp(-lv)
        v2f sd0, sd1, iv0, iv1;
        sd0.x = __expf(0.5f * lv0.x); sd0.y = __expf(0.5f * lv0.y);
        sd1.x = __expf(0.5f * lv1.x); sd1.y = __expf(0.5f * lv1.y);
        iv0.x = __expf(-lv0.x);       iv0.y = __expf(-lv0.y);
        iv1.x = __expf(-lv1.x);       iv1.y = __expf(-lv1.y);
        v2f e0; e0.x = ev[p][0]; e0.y = ev[p][2];
        v2f e1; e1.x = ev[p][1]; e1.y = ev[p][3];
        const v2f f0 = __builtin_elementwise_fma(sd0, e0, ms0);
        const v2f f1 = __builtin_elementwise_fma(sd1, e1, ms1);
        // -logp contribution
        v2f y0; y0.x = yv[p][0]; y0.y = yv[p][2];
        v2f y1; y1.x = yv[p][1]; y1.y = yv[p][3];
        const v2f d0 = y0 - ms0, d1 = y1 - ms1;
        const v2f q = __builtin_elementwise_fma(d0 * d0, iv0, (d1 * d1) * iv1);
        if (rp < n_pairs) {
            v4f fxv;
            fxv[0] = f0.x; fxv[1] = f1.x;   // row 2rp
            fxv[2] = f0.y; fxv[3] = f1.y;   // row 2rp+1
            __builtin_nontemporal_store(fxv, reinterpret_cast<v4f*>(fx_out) + rp);
            lsum = lsum + __builtin_elementwise_fma(splat(0.5f), q + lv0 + lv1,
                                                    splat(LOG_2PI));
        }
    }
    float ls = lsum.x + lsum.y;

    // reduce: wave shuffle -> LDS -> one partial per block (no atomics)
    #pragma unroll
    for (int off = 32; off; off >>= 1) ls += __shfl_xor(ls, off, 64);
    if ((t & 63) == 0) s_part[t >> 6] = ls;
    __syncthreads();
    if (t == 0) {
        float bs = 0.f;
        #pragma unroll
        for (int w = 0; w < BLOCK / 64; ++w) bs += s_part[w];
        block_part[blockIdx.x] = bs;
    }
}

// Sum GRID per-block partials -> logp_out. One block of 256 threads.
__launch_bounds__(BLOCK, 1)
__global__ void mdn_reduce_kernel(const float* __restrict__ block_part,
                                  float* __restrict__ logp_out)
{
    __shared__ float s_part[BLOCK / 64];
    const int t = threadIdx.x;
    float s = 0.f;
    #pragma unroll
    for (int k = 0; k < GRID / BLOCK; ++k) s += block_part[t + k * BLOCK];
    #pragma unroll
    for (int off = 32; off; off >>= 1) s += __shfl_xor(s, off, 64);
    if ((t & 63) == 0) s_part[t >> 6] = s;
    __syncthreads();
    if (t == 0) {
        float bs = 0.f;
        #pragma unroll
        for (int w = 0; w < BLOCK / 64; ++w) bs += s_part[w];
        *logp_out = bs;
    }
}

extern "C" void kernel_launch(void* const* d_in, const int* in_sizes, int n_in,
                              void* d_out, int out_size, void* d_ws, size_t ws_size,
                              hipStream_t stream) {
    const float* x   = (const float*)d_in[0];
    const float* y   = (const float*)d_in[1];
    const float* eps = (const float*)d_in[2];
    const float* W1  = (const float*)d_in[3];
    const float* b1  = (const float*)d_in[4];
    const float* W2  = (const float*)d_in[5];
    const float* b2  = (const float*)d_in[6];
    const float* Wv  = (const float*)d_in[7];

    const int B = in_sizes[0] / 2;          // rows
    const int n_pairs = B / 2;              // float4 row-pairs
    float* fx_out     = (float*)d_out;
    float* logp_out   = fx_out + (size_t)2 * B;   // scalar at flat index 2B
    float* block_part = (float*)d_ws;             // GRID floats of scratch

    mdn_kernel<<<GRID, BLOCK, 0, stream>>>(x, y, eps, W1, b1, W2, b2, Wv,
                                           fx_out, block_part, n_pairs);
    mdn_reduce_kernel<<<1, BLOCK, 0, stream>>>(block_part, logp_out);
}